// Round 8
// baseline (11509.742 us; speedup 1.0000x reference)
//
#include <hip/hip_runtime.h>
#include <math.h>

#define N_CTX 4096
#define DIM 512
#define NPERS 16
#define KTOT (NPERS * DIM)   // 8192
#define EPS_NN 0.1f
#define TOPK_K 30

#define BM 128
#define KC 32
#define LDW 140              // swizzled LDS row width (f32): 128 data + 12 max shift
#define NSTEP (KTOT / KC)    // 256

// column swizzle: matrix-row c lives at f32 offset c + 4*(c>>5) within the row
__device__ __forceinline__ int swc(int c) { return c + ((c >> 5) << 2); }

// write 4 staged k-slots (value = (a*w)*s, two RNE muls — numerics-locked)
#define ST4(BUF, KB, AV, WV, S)                       \
  (BUF)[((KB) + 0) * LDW + scol] = ((AV).x * (WV).x) * (S); \
  (BUF)[((KB) + 1) * LDW + scol] = ((AV).y * (WV).y) * (S); \
  (BUF)[((KB) + 2) * LDW + scol] = ((AV).z * (WV).z) * (S); \
  (BUF)[((KB) + 3) * LDW + scol] = ((AV).w * (WV).w) * (S);

// ---------------------------------------------------------------------------
// Kernel 1: invr[p][n] = 0.25 / max(||context[n] * weight[p]||, 1e-12)
// UNCHANGED (bit-identical invr required).
// ---------------------------------------------------------------------------
__global__ __launch_bounds__(256) void norms_kernel(
    const float* __restrict__ ctx, const float* __restrict__ w,
    float* __restrict__ invr) {
  int wid = threadIdx.x >> 6;
  int lane = threadIdx.x & 63;
  int gid = blockIdx.x * 4 + wid;          // 0 .. 65535
  int p = gid >> 12;
  int n = gid & (N_CTX - 1);
  const float4* c4 = reinterpret_cast<const float4*>(ctx + (size_t)n * DIM + lane * 8);
  const float4* w4 = reinterpret_cast<const float4*>(w + (size_t)p * DIM + lane * 8);
  float4 c0 = c4[0], c1 = c4[1];
  float4 w0 = w4[0], w1 = w4[1];
  float s = 0.f, v;
  v = c0.x * w0.x; s = fmaf(v, v, s);
  v = c0.y * w0.y; s = fmaf(v, v, s);
  v = c0.z * w0.z; s = fmaf(v, v, s);
  v = c0.w * w0.w; s = fmaf(v, v, s);
  v = c1.x * w1.x; s = fmaf(v, v, s);
  v = c1.y * w1.y; s = fmaf(v, v, s);
  v = c1.z * w1.z; s = fmaf(v, v, s);
  v = c1.w * w1.w; s = fmaf(v, v, s);
#pragma unroll
  for (int off = 32; off; off >>= 1) s += __shfl_down(s, off, 64);
  if (lane == 0) invr[(size_t)p * N_CTX + n] = 0.25f / fmaxf(sqrtf(s), 1e-12f);
}

// ---------------------------------------------------------------------------
// Kernel 2: fp32 VALU GEMM, BIT-IDENTICAL numerics to R2/R5/R7 passing runs:
//  - staged value = (a*w)*s  (two RNE muls)
//  - every acc element accumulates k = 0..8191 strictly ascending via fmaf
// R8 structure: DOUBLE-BUFFERED LDS, ONE barrier per step. Per step:
//   issue chunk0 loads(s+1) -> compute kk0..15 -> write chunk0 to other buf
//   + issue chunk1 loads    -> compute kk16..31 -> write chunk1 -> barrier.
// Prefetch live-range capped at 6 float4 (24 VGPR) to avoid R5's spills.
// ---------------------------------------------------------------------------
__global__ __launch_bounds__(256) void att_gemm(
    const float* __restrict__ ctx, const float* __restrict__ w,
    const float* __restrict__ invr, float* __restrict__ out) {
  // triangular unmap: bid -> (by, bx), by <= bx
  int bid = blockIdx.x;
  int by = 0;
  while (bid >= (by + 1) * 32 - ((by + 1) * by) / 2) ++by;
  const int bx = by + (bid - (by * 32 - (by * (by - 1)) / 2));

  __shared__ __align__(16) float As[2][KC * LDW];
  __shared__ __align__(16) float Bs[2][KC * LDW];

  const int t = threadIdx.x;
  const int tx = t & 15, ty = t >> 4;
  const int tx8 = tx * 8, ty8 = ty * 8;
  const int aoff = swc(ty8);
  const int boff = swc(tx8);
  const int Ro = by * BM, Co = bx * BM;

  const int srow = t >> 1;                  // staged matrix-row 0..127
  const int sh16 = (t & 1) * 16;            // which 16 k-slots this thread stages
  const int scol = swc(srow);               // staged LDS column (swizzled)

  const float* __restrict__ arow_g = ctx + (size_t)(Ro + srow) * DIM;
  const float* __restrict__ brow_g = ctx + (size_t)(Co + srow) * DIM;

  float acc[8][8];
#pragma unroll
  for (int i = 0; i < 8; ++i)
#pragma unroll
    for (int j = 0; j < 8; ++j) acc[i][j] = 0.f;

  // prologue: stage step 0 into buffer 0 (p=0, dbase=0)
  {
    const int dk = sh16;
    const float4 wv0 = *reinterpret_cast<const float4*>(w + dk);
    const float4 wv1 = *reinterpret_cast<const float4*>(w + dk + 4);
    const float4 wv2 = *reinterpret_cast<const float4*>(w + dk + 8);
    const float4 wv3 = *reinterpret_cast<const float4*>(w + dk + 12);
    const float4 av0 = *reinterpret_cast<const float4*>(arow_g + dk);
    const float4 av1 = *reinterpret_cast<const float4*>(arow_g + dk + 4);
    const float4 av2 = *reinterpret_cast<const float4*>(arow_g + dk + 8);
    const float4 av3 = *reinterpret_cast<const float4*>(arow_g + dk + 12);
    const float4 bv0 = *reinterpret_cast<const float4*>(brow_g + dk);
    const float4 bv1 = *reinterpret_cast<const float4*>(brow_g + dk + 4);
    const float4 bv2 = *reinterpret_cast<const float4*>(brow_g + dk + 8);
    const float4 bv3 = *reinterpret_cast<const float4*>(brow_g + dk + 12);
    const float sA = invr[Ro + srow];
    const float sB = invr[Co + srow];
    ST4(As[0], sh16 + 0,  av0, wv0, sA); ST4(As[0], sh16 + 4,  av1, wv1, sA);
    ST4(As[0], sh16 + 8,  av2, wv2, sA); ST4(As[0], sh16 + 12, av3, wv3, sA);
    ST4(Bs[0], sh16 + 0,  bv0, wv0, sB); ST4(Bs[0], sh16 + 4,  bv1, wv1, sB);
    ST4(Bs[0], sh16 + 8,  bv2, wv2, sB); ST4(Bs[0], sh16 + 12, bv3, wv3, sB);
    __syncthreads();
  }

  for (int s = 0; s < NSTEP; ++s) {
    const int cur = s & 1;
    const float* __restrict__ Acur = As[cur];
    const float* __restrict__ Bcur = Bs[cur];
    float* __restrict__ Anxt = As[cur ^ 1];
    float* __restrict__ Bnxt = Bs[cur ^ 1];

    const bool have = (s + 1 < NSTEP);
    const int k1 = (s + 1) * KC;
    const int dk1 = (k1 & (DIM - 1)) + sh16;

    float4 wv0, wv1, wv2, wv3, av0, av1, av2, av3, bv0, bv1, bv2, bv3;
    float sA = 0.f, sB = 0.f;

    // chunk0 prefetch (k-slots sh16+0..7 of step s+1)
    if (have) {
      const int p1 = k1 >> 9;
      const float* wrow = w + (size_t)p1 * DIM + dk1;
      wv0 = *reinterpret_cast<const float4*>(wrow);
      wv1 = *reinterpret_cast<const float4*>(wrow + 4);
      av0 = *reinterpret_cast<const float4*>(arow_g + dk1);
      av1 = *reinterpret_cast<const float4*>(arow_g + dk1 + 4);
      bv0 = *reinterpret_cast<const float4*>(brow_g + dk1);
      bv1 = *reinterpret_cast<const float4*>(brow_g + dk1 + 4);
      sA = invr[(size_t)p1 * N_CTX + Ro + srow];
      sB = invr[(size_t)p1 * N_CTX + Co + srow];
    }

    // compute kk = 0..15 (global-load latency hides under these FMAs)
#pragma unroll
    for (int kk = 0; kk < 16; ++kk) {
      const float* arow_l = &Acur[kk * LDW];
      const float* brow_l = &Bcur[kk * LDW];
      const float4 a0 = *reinterpret_cast<const float4*>(arow_l + aoff);
      const float4 a1 = *reinterpret_cast<const float4*>(arow_l + aoff + 4);
      const float4 b0 = *reinterpret_cast<const float4*>(brow_l + boff);
      const float4 b1 = *reinterpret_cast<const float4*>(brow_l + boff + 4);
      const float av[8] = {a0.x, a0.y, a0.z, a0.w, a1.x, a1.y, a1.z, a1.w};
      const float bv[8] = {b0.x, b0.y, b0.z, b0.w, b1.x, b1.y, b1.z, b1.w};
#pragma unroll
      for (int i = 0; i < 8; ++i)
#pragma unroll
        for (int j = 0; j < 8; ++j) acc[i][j] = fmaf(av[i], bv[j], acc[i][j]);
    }

    if (have) {
      // write chunk0 into the other buffer (nobody reads it this step)
      ST4(Anxt, sh16 + 0, av0, wv0, sA); ST4(Anxt, sh16 + 4, av1, wv1, sA);
      ST4(Bnxt, sh16 + 0, bv0, wv0, sB); ST4(Bnxt, sh16 + 4, bv1, wv1, sB);
      // chunk1 prefetch (k-slots sh16+8..15)
      const int p1 = k1 >> 9;
      const float* wrow = w + (size_t)p1 * DIM + dk1;
      wv2 = *reinterpret_cast<const float4*>(wrow + 8);
      wv3 = *reinterpret_cast<const float4*>(wrow + 12);
      av2 = *reinterpret_cast<const float4*>(arow_g + dk1 + 8);
      av3 = *reinterpret_cast<const float4*>(arow_g + dk1 + 12);
      bv2 = *reinterpret_cast<const float4*>(brow_g + dk1 + 8);
      bv3 = *reinterpret_cast<const float4*>(brow_g + dk1 + 12);
    }

    // compute kk = 16..31
#pragma unroll
    for (int kk = 16; kk < 32; ++kk) {
      const float* arow_l = &Acur[kk * LDW];
      const float* brow_l = &Bcur[kk * LDW];
      const float4 a0 = *reinterpret_cast<const float4*>(arow_l + aoff);
      const float4 a1 = *reinterpret_cast<const float4*>(arow_l + aoff + 4);
      const float4 b0 = *reinterpret_cast<const float4*>(brow_l + boff);
      const float4 b1 = *reinterpret_cast<const float4*>(brow_l + boff + 4);
      const float av[8] = {a0.x, a0.y, a0.z, a0.w, a1.x, a1.y, a1.z, a1.w};
      const float bv[8] = {b0.x, b0.y, b0.z, b0.w, b1.x, b1.y, b1.z, b1.w};
#pragma unroll
      for (int i = 0; i < 8; ++i)
#pragma unroll
        for (int j = 0; j < 8; ++j) acc[i][j] = fmaf(av[i], bv[j], acc[i][j]);
    }

    if (have) {
      ST4(Anxt, sh16 + 8, av2, wv2, sA); ST4(Anxt, sh16 + 12, av3, wv3, sA);
      ST4(Bnxt, sh16 + 8, bv2, wv2, sB); ST4(Bnxt, sh16 + 12, bv3, wv3, sB);
    }

    __syncthreads();   // next buffer fully staged; current buffer free
  }

  // epilogue: straight tile + mirrored tile (unchanged)
#pragma unroll
  for (int i = 0; i < 8; ++i) {
    size_t base = (size_t)(Ro + ty8 + i) * N_CTX + Co + tx8;
    *reinterpret_cast<float4*>(out + base) =
        make_float4(acc[i][0], acc[i][1], acc[i][2], acc[i][3]);
    *reinterpret_cast<float4*>(out + base + 4) =
        make_float4(acc[i][4], acc[i][5], acc[i][6], acc[i][7]);
  }
  if (bx != by) {
#pragma unroll
    for (int j = 0; j < 8; ++j) {
      size_t base = (size_t)(Co + tx8 + j) * N_CTX + Ro + ty8;
      *reinterpret_cast<float4*>(out + base) =
          make_float4(acc[0][j], acc[1][j], acc[2][j], acc[3][j]);
      *reinterpret_cast<float4*>(out + base + 4) =
          make_float4(acc[4][j], acc[5][j], acc[6][j], acc[7][j]);
    }
  }
}

// ---------------------------------------------------------------------------
// Kernel 3: per-row epsilon threshold + exact top-30 mask. UNCHANGED.
// ---------------------------------------------------------------------------
__global__ __launch_bounds__(256) void topk_kernel(float* __restrict__ att) {
  __shared__ unsigned red[4];
  __shared__ unsigned eqcnt[256];

  const int n = blockIdx.x;
  const int t = threadIdx.x;
  const int wid = t >> 6, lane = t & 63;
  float* row = att + (size_t)n * N_CTX;

  float vr[16];
  unsigned ur[16];
#pragma unroll
  for (int i = 0; i < 4; ++i) {
    float4 v4 = *reinterpret_cast<const float4*>(row + t * 16 + i * 4);
    float tmp[4] = {v4.x, v4.y, v4.z, v4.w};
#pragma unroll
    for (int j = 0; j < 4; ++j) {
      float v = tmp[j];
      v = (v > EPS_NN) ? v : 0.0f;
      vr[i * 4 + j] = v;
      ur[i * 4 + j] = __float_as_uint(v);
    }
  }

  unsigned lo = 0u, hi = 0x7F800000u;
  while (lo < hi) {
    unsigned mid = lo + ((hi - lo) >> 1);
    unsigned c = 0;
#pragma unroll
    for (int i = 0; i < 16; ++i) c += (ur[i] > mid) ? 1u : 0u;
#pragma unroll
    for (int off = 32; off; off >>= 1) c += __shfl_down(c, off, 64);
    if (lane == 0) red[wid] = c;
    __syncthreads();
    unsigned tot = red[0] + red[1] + red[2] + red[3];
    __syncthreads();
    if (tot < TOPK_K) hi = mid; else lo = mid + 1;
  }
  const unsigned kbits = lo;

  {
    unsigned c = 0;
#pragma unroll
    for (int i = 0; i < 16; ++i) c += (ur[i] > kbits) ? 1u : 0u;
#pragma unroll
    for (int off = 32; off; off >>= 1) c += __shfl_down(c, off, 64);
    if (lane == 0) red[wid] = c;
  }
  __syncthreads();
  const unsigned gt = red[0] + red[1] + red[2] + red[3];
  const unsigned r_eq = TOPK_K - gt;
  __syncthreads();

  unsigned ec = 0;
#pragma unroll
  for (int i = 0; i < 16; ++i) ec += (ur[i] == kbits) ? 1u : 0u;
  eqcnt[t] = ec;
  __syncthreads();
  for (int off = 1; off < 256; off <<= 1) {
    unsigned v = eqcnt[t];
    unsigned add = (t >= off) ? eqcnt[t - off] : 0u;
    __syncthreads();
    eqcnt[t] = v + add;
    __syncthreads();
  }
  const unsigned prefix = eqcnt[t] - ec;

  unsigned seen = 0;
#pragma unroll
  for (int i = 0; i < 16; ++i) {
    float o = 0.0f;
    if (ur[i] > kbits) {
      o = vr[i];
    } else if (kbits != 0u && ur[i] == kbits) {
      if (prefix + seen < r_eq) o = vr[i];
      ++seen;
    }
    vr[i] = o;
  }
#pragma unroll
  for (int i = 0; i < 4; ++i) {
    *reinterpret_cast<float4*>(row + t * 16 + i * 4) =
        make_float4(vr[i * 4], vr[i * 4 + 1], vr[i * 4 + 2], vr[i * 4 + 3]);
  }
}

// ---------------------------------------------------------------------------
extern "C" void kernel_launch(void* const* d_in, const int* in_sizes, int n_in,
                              void* d_out, int out_size, void* d_ws, size_t ws_size,
                              hipStream_t stream) {
  const float* ctx = (const float*)d_in[0];   // (4096, 512)
  const float* w   = (const float*)d_in[1];   // (16, 512)
  float* out = (float*)d_out;                 // (4096, 4096)
  float* invr = (float*)d_ws;                 // 16*4096 f32 = 256 KB scratch

  norms_kernel<<<(NPERS * N_CTX) / 4, 256, 0, stream>>>(ctx, w, invr);

  att_gemm<<<528, 256, 0, stream>>>(ctx, w, invr, out);   // triangular grid

  topk_kernel<<<N_CTX, 256, 0, stream>>>(out);
}

// Round 9
// 1742.294 us; speedup vs baseline: 6.6061x; 6.6061x over previous
//
#include <hip/hip_runtime.h>
#include <math.h>

#define N_CTX 4096
#define DIM 512
#define NPERS 16
#define KTOT (NPERS * DIM)   // 8192
#define EPS_NN 0.1f
#define TOPK_K 30

#define DELTA 1e-3f          // ambiguity margin (>> 3e-5 worst approx error)
#define CAP 64               // max candidates per row

#define BM 128               // MFMA output tile
#define BK 64                // K-step (bf16 elems)

typedef __attribute__((ext_vector_type(8))) short bfrag;   // 8 bf16 = 4 VGPR
typedef __attribute__((ext_vector_type(4))) float f32x4;

// round-to-nearest-even float -> bf16 bits
__device__ __forceinline__ unsigned short f2bf(float f) {
  unsigned u = __float_as_uint(f);
  unsigned r = u + 0x7FFFu + ((u >> 16) & 1u);
  return (unsigned short)(r >> 16);
}

// ---------------------------------------------------------------------------
// Kernel 1: invr[p][n] = 0.25 / max(||context[n] * weight[p]||, 1e-12)
// UNCHANGED (bit-identical invr feeds both GEMM and exact repair).
// ---------------------------------------------------------------------------
__global__ __launch_bounds__(256) void norms_kernel(
    const float* __restrict__ ctx, const float* __restrict__ w,
    float* __restrict__ invr) {
  int wid = threadIdx.x >> 6;
  int lane = threadIdx.x & 63;
  int gid = blockIdx.x * 4 + wid;          // 0 .. 65535
  int p = gid >> 12;
  int n = gid & (N_CTX - 1);
  const float4* c4 = reinterpret_cast<const float4*>(ctx + (size_t)n * DIM + lane * 8);
  const float4* w4 = reinterpret_cast<const float4*>(w + (size_t)p * DIM + lane * 8);
  float4 c0 = c4[0], c1 = c4[1];
  float4 w0 = w4[0], w1 = w4[1];
  float s = 0.f, v;
  v = c0.x * w0.x; s = fmaf(v, v, s);
  v = c0.y * w0.y; s = fmaf(v, v, s);
  v = c0.z * w0.z; s = fmaf(v, v, s);
  v = c0.w * w0.w; s = fmaf(v, v, s);
  v = c1.x * w1.x; s = fmaf(v, v, s);
  v = c1.y * w1.y; s = fmaf(v, v, s);
  v = c1.z * w1.z; s = fmaf(v, v, s);
  v = c1.w * w1.w; s = fmaf(v, v, s);
#pragma unroll
  for (int off = 32; off; off >>= 1) s += __shfl_down(s, off, 64);
  if (lane == 0) invr[(size_t)p * N_CTX + n] = 0.25f / fmaxf(sqrtf(s), 1e-12f);
}

// ---------------------------------------------------------------------------
// Kernel 2: approximate att = F F^T via bf16 MFMA, Ootomo hi/lo 3 products.
// (R3 kernel verbatim — values good to ~1e-5; boundary decisions repaired
// later by exact recompute.)
// ---------------------------------------------------------------------------
#define SWZ(r, b) ((b) ^ (((r) & 7) << 4))

__device__ __forceinline__ void stage_half(char* __restrict__ hi_base,
                                           char* __restrict__ lo_base,
                                           const float4* cv, const float4* wv,
                                           float s, int r, int h) {
  unsigned hu[16], lu[16];
#pragma unroll
  for (int i = 0; i < 8; ++i) {
    float f[4] = {cv[i].x * wv[i].x * s, cv[i].y * wv[i].y * s,
                  cv[i].z * wv[i].z * s, cv[i].w * wv[i].w * s};
    unsigned hb[4], lb[4];
#pragma unroll
    for (int j = 0; j < 4; ++j) {
      hb[j] = f2bf(f[j]);
      float hf = __uint_as_float(hb[j] << 16);
      lb[j] = f2bf(f[j] - hf);
    }
    hu[2 * i] = hb[0] | (hb[1] << 16);
    hu[2 * i + 1] = hb[2] | (hb[3] << 16);
    lu[2 * i] = lb[0] | (lb[1] << 16);
    lu[2 * i + 1] = lb[2] | (lb[3] << 16);
  }
#pragma unroll
  for (int c = 0; c < 4; ++c) {
    int boff = r * 128 + SWZ(r, h * 64 + c * 16);
    *reinterpret_cast<uint4*>(hi_base + boff) =
        make_uint4(hu[4 * c], hu[4 * c + 1], hu[4 * c + 2], hu[4 * c + 3]);
    *reinterpret_cast<uint4*>(lo_base + boff) =
        make_uint4(lu[4 * c], lu[4 * c + 1], lu[4 * c + 2], lu[4 * c + 3]);
  }
}

__global__ __launch_bounds__(256, 2) void att_gemm(
    const float* __restrict__ ctx, const float* __restrict__ w,
    const float* __restrict__ invr, float* __restrict__ out) {
  const int bx = blockIdx.x, by = blockIdx.y;
  if (by > bx) return;                      // symmetric: upper triangle only

  __shared__ __align__(16) char Ahi[BM * 128];
  __shared__ __align__(16) char Alo[BM * 128];
  __shared__ __align__(16) char Bhi[BM * 128];
  __shared__ __align__(16) char Blo[BM * 128];

  const int t = threadIdx.x;
  const int lane = t & 63, wid = t >> 6;
  const int wr = wid >> 1, wc = wid & 1;    // wave's 64x64 quadrant
  const int Ro = by * BM, Co = bx * BM;

  const int srow = t >> 1;                  // staged row 0..127
  const int sh = t & 1;                     // which 32-elem half of the 64 cols

  f32x4 acc[4][4] = {};

  for (int k0 = 0; k0 < KTOT; k0 += BK) {
    const int p = k0 >> 9;
    const int d0 = (k0 & (DIM - 1)) + sh * 32;

    float4 cva[8], cvb[8], wv[8];
    const float* wrow = w + (size_t)p * DIM + d0;
    const float* arow = ctx + (size_t)(Ro + srow) * DIM + d0;
    const float* brow = ctx + (size_t)(Co + srow) * DIM + d0;
#pragma unroll
    for (int i = 0; i < 8; ++i) {
      wv[i] = *reinterpret_cast<const float4*>(wrow + 4 * i);
      cva[i] = *reinterpret_cast<const float4*>(arow + 4 * i);
      cvb[i] = *reinterpret_cast<const float4*>(brow + 4 * i);
    }
    const float sA = invr[(size_t)p * N_CTX + Ro + srow];
    const float sB = invr[(size_t)p * N_CTX + Co + srow];

    __syncthreads();   // previous iteration's ds_reads complete

    stage_half(Ahi, Alo, cva, wv, sA, srow, sh);
    stage_half(Bhi, Blo, cvb, wv, sB, srow, sh);

    __syncthreads();   // staged data visible

#pragma unroll
    for (int ks = 0; ks < 2; ++ks) {
      const int kb = ks * 64 + (lane >> 4) * 16;
      bfrag ah[4], al[4], bh[4], bl[4];
#pragma unroll
      for (int m = 0; m < 4; ++m) {
        const int r = wr * 64 + m * 16 + (lane & 15);
        const int off = r * 128 + SWZ(r, kb);
        ah[m] = *reinterpret_cast<const bfrag*>(Ahi + off);
        al[m] = *reinterpret_cast<const bfrag*>(Alo + off);
      }
#pragma unroll
      for (int n = 0; n < 4; ++n) {
        const int r = wc * 64 + n * 16 + (lane & 15);
        const int off = r * 128 + SWZ(r, kb);
        bh[n] = *reinterpret_cast<const bfrag*>(Bhi + off);
        bl[n] = *reinterpret_cast<const bfrag*>(Blo + off);
      }
#pragma unroll
      for (int m = 0; m < 4; ++m)
#pragma unroll
        for (int n = 0; n < 4; ++n) {
          acc[m][n] = __builtin_amdgcn_mfma_f32_16x16x32_bf16(ah[m], bh[n], acc[m][n], 0, 0, 0);
          acc[m][n] = __builtin_amdgcn_mfma_f32_16x16x32_bf16(ah[m], bl[n], acc[m][n], 0, 0, 0);
          acc[m][n] = __builtin_amdgcn_mfma_f32_16x16x32_bf16(al[m], bh[n], acc[m][n], 0, 0, 0);
        }
    }
  }

  // epilogue: C/D layout col = lane&15, row = (lane>>4)*4 + reg
  const int col = lane & 15, rq = (lane >> 4) * 4;
#pragma unroll
  for (int m = 0; m < 4; ++m)
#pragma unroll
    for (int n = 0; n < 4; ++n) {
      const int gr = Ro + wr * 64 + m * 16 + rq;
      const int gc = Co + wc * 64 + n * 16 + col;
#pragma unroll
      for (int j = 0; j < 4; ++j)
        out[(size_t)(gr + j) * N_CTX + gc] = acc[m][n][j];
      if (bx != by) {   // mirrored tile
        *reinterpret_cast<float4*>(out + (size_t)gc * N_CTX + gr) =
            make_float4(acc[m][n][0], acc[m][n][1], acc[m][n][2], acc[m][n][3]);
      }
    }
}

// ---------------------------------------------------------------------------
// Kernel 3: scan. Per row: approx eps-threshold, binary-search approx 30th
// value vk, classify: definite-in (write approx) / candidate (write 0,
// record) / definite-out (write 0). Store g (definite-in count) and count.
// ---------------------------------------------------------------------------
__global__ __launch_bounds__(256) void topk_scan(
    float* __restrict__ att, int* __restrict__ candM,
    int* __restrict__ cnt_g) {
  __shared__ unsigned red[4];
  __shared__ int lcnt, lg;

  const int n = blockIdx.x;
  const int t = threadIdx.x;
  const int wid = t >> 6, lane = t & 63;
  float* row = att + (size_t)n * N_CTX;

  float ar[16], tr[16];
  unsigned ur[16];
#pragma unroll
  for (int i = 0; i < 4; ++i) {
    float4 v4 = *reinterpret_cast<const float4*>(row + t * 16 + i * 4);
    float tmp[4] = {v4.x, v4.y, v4.z, v4.w};
#pragma unroll
    for (int j = 0; j < 4; ++j) {
      float a = tmp[j];
      float tt = (a > EPS_NN) ? a : 0.0f;
      ar[i * 4 + j] = a;
      tr[i * 4 + j] = tt;
      ur[i * 4 + j] = __float_as_uint(tt);
    }
  }

  // binary search: smallest u with count(bits > u) < K  => u = bits(30th)
  unsigned lo = 0u, hi = 0x7F800000u;
  while (lo < hi) {
    unsigned mid = lo + ((hi - lo) >> 1);
    unsigned c = 0;
#pragma unroll
    for (int i = 0; i < 16; ++i) c += (ur[i] > mid) ? 1u : 0u;
#pragma unroll
    for (int off = 32; off; off >>= 1) c += __shfl_down(c, off, 64);
    if (lane == 0) red[wid] = c;
    __syncthreads();
    unsigned tot = red[0] + red[1] + red[2] + red[3];
    __syncthreads();
    if (tot < TOPK_K) hi = mid; else lo = mid + 1;
  }
  const float vk = __uint_as_float(lo);

  if (t == 0) { lcnt = 0; lg = 0; }
  __syncthreads();

  unsigned myg = 0;
#pragma unroll
  for (int i = 0; i < 16; ++i) {
    const int m = t * 16 + i;
    const float a = ar[i], tt = tr[i];
    const bool isEps = fabsf(a - EPS_NN) <= DELTA;
    const bool isOrd = (tt > 0.f) && (fabsf(tt - vk) <= DELTA);
    const bool cand = isEps || isOrd;
    const bool defIn = (tt > vk + DELTA) && !cand;
    tr[i] = defIn ? tt : 0.f;        // output value
    myg += defIn ? 1u : 0u;
    if (cand) {
      int pos = atomicAdd(&lcnt, 1);
      if (pos < CAP) candM[n * CAP + pos] = m;
    }
  }
#pragma unroll
  for (int off = 32; off; off >>= 1) myg += __shfl_down(myg, off, 64);
  if (lane == 0) atomicAdd(&lg, (int)myg);

#pragma unroll
  for (int i = 0; i < 4; ++i) {
    *reinterpret_cast<float4*>(row + t * 16 + i * 4) =
        make_float4(tr[i * 4], tr[i * 4 + 1], tr[i * 4 + 2], tr[i * 4 + 3]);
  }
  __syncthreads();
  if (t == 0) {
    cnt_g[2 * n] = (lcnt < CAP) ? lcnt : CAP;
    cnt_g[2 * n + 1] = lg;
  }
}

// ---------------------------------------------------------------------------
// Kernel 4: exact repair + select. Per row with candidates: recompute each
// candidate BIT-IDENTICALLY to the R2/R7 fp32 kernel (staged (a*w)*s, fmaf
// over k=0..8191 ascending), eps-threshold, rank by (value desc, idx asc),
// keep top-(30 - g).
// ---------------------------------------------------------------------------
__global__ __launch_bounds__(64) void repair_select(
    const float* __restrict__ ctx, const float* __restrict__ w,
    const float* __restrict__ invr, const int* __restrict__ candM,
    const int* __restrict__ cnt_g, float* __restrict__ att) {
  const int n = blockIdx.x;
  const int c = cnt_g[2 * n];
  if (c == 0) return;
  const int slots = TOPK_K - cnt_g[2 * n + 1];

  __shared__ float te_s[CAP];
  __shared__ int m_s[CAP];

  const int j = threadIdx.x;
  float te = -1.f;
  int m = -1;
  if (j < c) {
    m = candM[n * CAP + j];
    const float* cn = ctx + (size_t)n * DIM;
    const float* cm = ctx + (size_t)m * DIM;
    float e = 0.f;
    for (int p = 0; p < NPERS; ++p) {
      const float sA = invr[(size_t)p * N_CTX + n];
      const float sB = invr[(size_t)p * N_CTX + m];
      const float* wp = w + (size_t)p * DIM;
      for (int d = 0; d < DIM; ++d)
        e = fmaf((cn[d] * wp[d]) * sA, (cm[d] * wp[d]) * sB, e);
    }
    te = (e > EPS_NN) ? e : 0.f;
  }
  m_s[j] = m;
  te_s[j] = te;
  __syncthreads();
  if (j < c) {
    int rank = 0;
    for (int i = 0; i < c; ++i) {
      if (i == j) continue;
      rank += ((te_s[i] > te) || (te_s[i] == te && m_s[i] < m)) ? 1 : 0;
    }
    if (rank < slots) att[(size_t)n * N_CTX + m] = te;
  }
}

// ---------------------------------------------------------------------------
extern "C" void kernel_launch(void* const* d_in, const int* in_sizes, int n_in,
                              void* d_out, int out_size, void* d_ws, size_t ws_size,
                              hipStream_t stream) {
  const float* ctx = (const float*)d_in[0];   // (4096, 512)
  const float* w   = (const float*)d_in[1];   // (16, 512)
  float* out = (float*)d_out;                 // (4096, 4096)

  // ws layout: invr (256 KB) | cnt_g (32 KB) | candM (1 MB)
  float* invr = (float*)d_ws;
  int* cnt_g = (int*)((char*)d_ws + (NPERS * N_CTX) * sizeof(float));
  int* candM = (int*)((char*)cnt_g + 2 * N_CTX * sizeof(int));

  norms_kernel<<<(NPERS * N_CTX) / 4, 256, 0, stream>>>(ctx, w, invr);

  dim3 grid(N_CTX / BM, N_CTX / BM);          // 32 x 32, lower half early-exits
  att_gemm<<<grid, 256, 0, stream>>>(ctx, w, invr, out);

  topk_scan<<<N_CTX, 256, 0, stream>>>(out, candM, cnt_g);

  repair_select<<<N_CTX, 64, 0, stream>>>(ctx, w, invr, candM, cnt_g, out);
}

// Round 10
// 1014.567 us; speedup vs baseline: 11.3445x; 1.7173x over previous
//
#include <hip/hip_runtime.h>
#include <math.h>
#include <stdint.h>

#define N_CTX 4096
#define DIM 512
#define NPERS 16
#define KTOT (NPERS * DIM)   // 8192
#define EPS_NN 0.1f
#define TOPK_K 30

#define DELTA 1e-3f          // ambiguity margin (>> worst approx-vs-exact error)
#define CAP 64               // max candidates per row

#define BM 128               // MFMA output tile
#define BK 64                // K-step (bf16 elems)
#define NKSTEP (KTOT / BK)   // 128
#define CHUNK 16384          // bytes per (panel, k-step) LDS image

typedef __attribute__((ext_vector_type(8))) short bfrag;   // 8 bf16 = 4 VGPR
typedef __attribute__((ext_vector_type(4))) float f32x4;

// round-to-nearest-even float -> bf16 bits
__device__ __forceinline__ unsigned short f2bf(float f) {
  unsigned u = __float_as_uint(f);
  unsigned r = u + 0x7FFFu + ((u >> 16) & 1u);
  return (unsigned short)(r >> 16);
}

#define SWZ(r, b) ((b) ^ (((r) & 7) << 4))

// stage 1 KB: 64 lanes x 16 B. ldst = wave-uniform LDS base; HW adds lane*16.
__device__ __forceinline__ void stage1k(const char* gsrc, char* ldst, int lane) {
#if __has_builtin(__builtin_amdgcn_global_load_lds)
  __builtin_amdgcn_global_load_lds(
      (const __attribute__((address_space(1))) unsigned int*)(uintptr_t)(gsrc + lane * 16),
      (__attribute__((address_space(3))) unsigned int*)(uintptr_t)ldst, 16, 0, 0);
#else
  *reinterpret_cast<uint4*>(ldst + lane * 16) =
      *reinterpret_cast<const uint4*>(gsrc + lane * 16);
#endif
}

// ---------------------------------------------------------------------------
// Kernel 1: invr[p][n] = 0.25 / max(||context[n] * weight[p]||, 1e-12)
// UNCHANGED (bit-identical invr feeds split, fallback GEMM and exact repair).
// ---------------------------------------------------------------------------
__global__ __launch_bounds__(256) void norms_kernel(
    const float* __restrict__ ctx, const float* __restrict__ w,
    float* __restrict__ invr) {
  int wid = threadIdx.x >> 6;
  int lane = threadIdx.x & 63;
  int gid = blockIdx.x * 4 + wid;          // 0 .. 65535
  int p = gid >> 12;
  int n = gid & (N_CTX - 1);
  const float4* c4 = reinterpret_cast<const float4*>(ctx + (size_t)n * DIM + lane * 8);
  const float4* w4 = reinterpret_cast<const float4*>(w + (size_t)p * DIM + lane * 8);
  float4 c0 = c4[0], c1 = c4[1];
  float4 w0 = w4[0], w1 = w4[1];
  float s = 0.f, v;
  v = c0.x * w0.x; s = fmaf(v, v, s);
  v = c0.y * w0.y; s = fmaf(v, v, s);
  v = c0.z * w0.z; s = fmaf(v, v, s);
  v = c0.w * w0.w; s = fmaf(v, v, s);
  v = c1.x * w1.x; s = fmaf(v, v, s);
  v = c1.y * w1.y; s = fmaf(v, v, s);
  v = c1.z * w1.z; s = fmaf(v, v, s);
  v = c1.w * w1.w; s = fmaf(v, v, s);
#pragma unroll
  for (int off = 32; off; off >>= 1) s += __shfl_down(s, off, 64);
  if (lane == 0) invr[(size_t)p * N_CTX + n] = 0.25f / fmaxf(sqrtf(s), 1e-12f);
}

// ---------------------------------------------------------------------------
// Kernel 1b: split F = hi + lo (bf16 RNE each, EXACT same arithmetic as R9's
// stage_half) into panel-swizzled LDS-image layout:
//   chunk (P, s) at byte (P*128+s)*16384; within: r*128 + ((sl*16)^((r&7)<<4))
// One thread per 16-byte slot (8 bf16).
// ---------------------------------------------------------------------------
__global__ __launch_bounds__(256) void split_kernel(
    const float* __restrict__ ctx, const float* __restrict__ w,
    const float* __restrict__ invr, unsigned short* __restrict__ Fhi,
    unsigned short* __restrict__ Flo) {
  const int tid = blockIdx.x * 256 + threadIdx.x;
  const int chunkid = tid >> 10;          // 0..4095  (P*128 + s)
  const int q = tid & 1023;
  const int r = q >> 3;                   // row within panel 0..127
  const int sl = q & 7;                   // 16B slot 0..7
  const int P = chunkid >> 7;
  const int s = chunkid & 127;
  const int n = P * 128 + r;
  const int k0 = s * BK + sl * 8;
  const int p = k0 >> 9;
  const int d0 = k0 & (DIM - 1);

  const float4 c0 = *reinterpret_cast<const float4*>(ctx + (size_t)n * DIM + d0);
  const float4 c1 = *reinterpret_cast<const float4*>(ctx + (size_t)n * DIM + d0 + 4);
  const float4 w0 = *reinterpret_cast<const float4*>(w + (size_t)p * DIM + d0);
  const float4 w1 = *reinterpret_cast<const float4*>(w + (size_t)p * DIM + d0 + 4);
  const float sc = invr[(size_t)p * N_CTX + n];

  float f[8] = {c0.x * w0.x * sc, c0.y * w0.y * sc, c0.z * w0.z * sc, c0.w * w0.w * sc,
                c1.x * w1.x * sc, c1.y * w1.y * sc, c1.z * w1.z * sc, c1.w * w1.w * sc};
  unsigned hb[8], lb[8];
#pragma unroll
  for (int j = 0; j < 8; ++j) {
    hb[j] = f2bf(f[j]);
    float hf = __uint_as_float(hb[j] << 16);
    lb[j] = f2bf(f[j] - hf);
  }
  uint4 hv = make_uint4(hb[0] | (hb[1] << 16), hb[2] | (hb[3] << 16),
                        hb[4] | (hb[5] << 16), hb[6] | (hb[7] << 16));
  uint4 lv = make_uint4(lb[0] | (lb[1] << 16), lb[2] | (lb[3] << 16),
                        lb[4] | (lb[5] << 16), lb[6] | (lb[7] << 16));
  const size_t base = (size_t)chunkid * CHUNK + r * 128 + ((sl * 16) ^ ((r & 7) << 4));
  *reinterpret_cast<uint4*>((char*)Fhi + base) = hv;
  *reinterpret_cast<uint4*>((char*)Flo + base) = lv;
}

// ---------------------------------------------------------------------------
// Kernel 2 (fast): att = F F^T via bf16 MFMA, 3 products (hh, hl, lh).
// Tiles staged from pre-split Fhi/Flo with global_load_lds (m97 2-barrier,
// single buffer). Accumulation order identical to R9 -> bit-identical output.
// Triangular 528-block grid.
// ---------------------------------------------------------------------------
__global__ __launch_bounds__(256, 2) void att_gemm_fast(
    const unsigned short* __restrict__ Fhi, const unsigned short* __restrict__ Flo,
    float* __restrict__ out) {
  int bid = blockIdx.x;
  int by = 0;
  while (bid >= (by + 1) * 32 - ((by + 1) * by) / 2) ++by;
  const int bx = by + (bid - (by * 32 - (by * (by - 1)) / 2));

  __shared__ __align__(16) char Ahi[CHUNK];
  __shared__ __align__(16) char Alo[CHUNK];
  __shared__ __align__(16) char Bhi[CHUNK];
  __shared__ __align__(16) char Blo[CHUNK];

  const int t = threadIdx.x;
  const int lane = t & 63, wid = t >> 6;
  const int wr = wid >> 1, wc = wid & 1;
  const int woff = __builtin_amdgcn_readfirstlane(wid * 4096);

  const char* gAh = (const char*)Fhi + (size_t)by * NKSTEP * CHUNK + woff;
  const char* gAl = (const char*)Flo + (size_t)by * NKSTEP * CHUNK + woff;
  const char* gBh = (const char*)Fhi + (size_t)bx * NKSTEP * CHUNK + woff;
  const char* gBl = (const char*)Flo + (size_t)bx * NKSTEP * CHUNK + woff;

  f32x4 acc[4][4] = {};

  for (int s = 0; s < NKSTEP; ++s) {
    const size_t so = (size_t)s * CHUNK;
#pragma unroll
    for (int i = 0; i < 4; ++i) {
      stage1k(gAh + so + i * 1024, Ahi + woff + i * 1024, lane);
      stage1k(gAl + so + i * 1024, Alo + woff + i * 1024, lane);
      stage1k(gBh + so + i * 1024, Bhi + woff + i * 1024, lane);
      stage1k(gBl + so + i * 1024, Blo + woff + i * 1024, lane);
    }
    __syncthreads();   // vmcnt drained before barrier: staged data visible

#pragma unroll
    for (int ks = 0; ks < 2; ++ks) {
      const int kb = ks * 64 + (lane >> 4) * 16;
      bfrag ah[4], al[4], bh[4], bl[4];
#pragma unroll
      for (int m = 0; m < 4; ++m) {
        const int r = wr * 64 + m * 16 + (lane & 15);
        const int off = r * 128 + SWZ(r, kb);
        ah[m] = *reinterpret_cast<const bfrag*>(Ahi + off);
        al[m] = *reinterpret_cast<const bfrag*>(Alo + off);
      }
#pragma unroll
      for (int n2 = 0; n2 < 4; ++n2) {
        const int r = wc * 64 + n2 * 16 + (lane & 15);
        const int off = r * 128 + SWZ(r, kb);
        bh[n2] = *reinterpret_cast<const bfrag*>(Bhi + off);
        bl[n2] = *reinterpret_cast<const bfrag*>(Blo + off);
      }
#pragma unroll
      for (int m = 0; m < 4; ++m)
#pragma unroll
        for (int n2 = 0; n2 < 4; ++n2) {
          acc[m][n2] = __builtin_amdgcn_mfma_f32_16x16x32_bf16(ah[m], bh[n2], acc[m][n2], 0, 0, 0);
          acc[m][n2] = __builtin_amdgcn_mfma_f32_16x16x32_bf16(ah[m], bl[n2], acc[m][n2], 0, 0, 0);
          acc[m][n2] = __builtin_amdgcn_mfma_f32_16x16x32_bf16(al[m], bh[n2], acc[m][n2], 0, 0, 0);
        }
    }
    __syncthreads();   // all waves done reading before next overwrite
  }

  const int Ro = by * BM, Co = bx * BM;
  const int col = lane & 15, rq = (lane >> 4) * 4;
#pragma unroll
  for (int m = 0; m < 4; ++m)
#pragma unroll
    for (int n2 = 0; n2 < 4; ++n2) {
      const int gr = Ro + wr * 64 + m * 16 + rq;
      const int gc = Co + wc * 64 + n2 * 16 + col;
#pragma unroll
      for (int j = 0; j < 4; ++j)
        out[(size_t)(gr + j) * N_CTX + gc] = acc[m][n2][j];
      if (bx != by) {
        *reinterpret_cast<float4*>(out + (size_t)gc * N_CTX + gr) =
            make_float4(acc[m][n2][0], acc[m][n2][1], acc[m][n2][2], acc[m][n2][3]);
      }
    }
}

// ---------------------------------------------------------------------------
// Kernel 2 (fallback, R9 verbatim): on-the-fly split + MFMA. Used only if
// ws_size can't hold Fhi/Flo.
// ---------------------------------------------------------------------------
__device__ __forceinline__ void stage_half(char* __restrict__ hi_base,
                                           char* __restrict__ lo_base,
                                           const float4* cv, const float4* wv,
                                           float s, int r, int h) {
  unsigned hu[16], lu[16];
#pragma unroll
  for (int i = 0; i < 8; ++i) {
    float f[4] = {cv[i].x * wv[i].x * s, cv[i].y * wv[i].y * s,
                  cv[i].z * wv[i].z * s, cv[i].w * wv[i].w * s};
    unsigned hb[4], lb[4];
#pragma unroll
    for (int j = 0; j < 4; ++j) {
      hb[j] = f2bf(f[j]);
      float hf = __uint_as_float(hb[j] << 16);
      lb[j] = f2bf(f[j] - hf);
    }
    hu[2 * i] = hb[0] | (hb[1] << 16);
    hu[2 * i + 1] = hb[2] | (hb[3] << 16);
    lu[2 * i] = lb[0] | (lb[1] << 16);
    lu[2 * i + 1] = lb[2] | (lb[3] << 16);
  }
#pragma unroll
  for (int c = 0; c < 4; ++c) {
    int boff = r * 128 + SWZ(r, h * 64 + c * 16);
    *reinterpret_cast<uint4*>(hi_base + boff) =
        make_uint4(hu[4 * c], hu[4 * c + 1], hu[4 * c + 2], hu[4 * c + 3]);
    *reinterpret_cast<uint4*>(lo_base + boff) =
        make_uint4(lu[4 * c], lu[4 * c + 1], lu[4 * c + 2], lu[4 * c + 3]);
  }
}

__global__ __launch_bounds__(256, 2) void att_gemm(
    const float* __restrict__ ctx, const float* __restrict__ w,
    const float* __restrict__ invr, float* __restrict__ out) {
  const int bx = blockIdx.x, by = blockIdx.y;
  if (by > bx) return;

  __shared__ __align__(16) char Ahi[BM * 128];
  __shared__ __align__(16) char Alo[BM * 128];
  __shared__ __align__(16) char Bhi[BM * 128];
  __shared__ __align__(16) char Blo[BM * 128];

  const int t = threadIdx.x;
  const int lane = t & 63, wid = t >> 6;
  const int wr = wid >> 1, wc = wid & 1;
  const int Ro = by * BM, Co = bx * BM;
  const int srow = t >> 1;
  const int sh = t & 1;

  f32x4 acc[4][4] = {};

  for (int k0 = 0; k0 < KTOT; k0 += BK) {
    const int p = k0 >> 9;
    const int d0 = (k0 & (DIM - 1)) + sh * 32;

    float4 cva[8], cvb[8], wv[8];
    const float* wrow = w + (size_t)p * DIM + d0;
    const float* arow = ctx + (size_t)(Ro + srow) * DIM + d0;
    const float* brow = ctx + (size_t)(Co + srow) * DIM + d0;
#pragma unroll
    for (int i = 0; i < 8; ++i) {
      wv[i] = *reinterpret_cast<const float4*>(wrow + 4 * i);
      cva[i] = *reinterpret_cast<const float4*>(arow + 4 * i);
      cvb[i] = *reinterpret_cast<const float4*>(brow + 4 * i);
    }
    const float sA = invr[(size_t)p * N_CTX + Ro + srow];
    const float sB = invr[(size_t)p * N_CTX + Co + srow];

    __syncthreads();
    stage_half(Ahi, Alo, cva, wv, sA, srow, sh);
    stage_half(Bhi, Blo, cvb, wv, sB, srow, sh);
    __syncthreads();

#pragma unroll
    for (int ks = 0; ks < 2; ++ks) {
      const int kb = ks * 64 + (lane >> 4) * 16;
      bfrag ah[4], al[4], bh[4], bl[4];
#pragma unroll
      for (int m = 0; m < 4; ++m) {
        const int r = wr * 64 + m * 16 + (lane & 15);
        const int off = r * 128 + SWZ(r, kb);
        ah[m] = *reinterpret_cast<const bfrag*>(Ahi + off);
        al[m] = *reinterpret_cast<const bfrag*>(Alo + off);
      }
#pragma unroll
      for (int n = 0; n < 4; ++n) {
        const int r = wc * 64 + n * 16 + (lane & 15);
        const int off = r * 128 + SWZ(r, kb);
        bh[n] = *reinterpret_cast<const bfrag*>(Bhi + off);
        bl[n] = *reinterpret_cast<const bfrag*>(Blo + off);
      }
#pragma unroll
      for (int m = 0; m < 4; ++m)
#pragma unroll
        for (int n = 0; n < 4; ++n) {
          acc[m][n] = __builtin_amdgcn_mfma_f32_16x16x32_bf16(ah[m], bh[n], acc[m][n], 0, 0, 0);
          acc[m][n] = __builtin_amdgcn_mfma_f32_16x16x32_bf16(ah[m], bl[n], acc[m][n], 0, 0, 0);
          acc[m][n] = __builtin_amdgcn_mfma_f32_16x16x32_bf16(al[m], bh[n], acc[m][n], 0, 0, 0);
        }
    }
  }

  const int col = lane & 15, rq = (lane >> 4) * 4;
#pragma unroll
  for (int m = 0; m < 4; ++m)
#pragma unroll
    for (int n = 0; n < 4; ++n) {
      const int gr = Ro + wr * 64 + m * 16 + rq;
      const int gc = Co + wc * 64 + n * 16 + col;
#pragma unroll
      for (int j = 0; j < 4; ++j)
        out[(size_t)(gr + j) * N_CTX + gc] = acc[m][n][j];
      if (bx != by) {
        *reinterpret_cast<float4*>(out + (size_t)gc * N_CTX + gr) =
            make_float4(acc[m][n][0], acc[m][n][1], acc[m][n][2], acc[m][n][3]);
      }
    }
}

// ---------------------------------------------------------------------------
// Kernel 3: scan (UNCHANGED from R9).
// ---------------------------------------------------------------------------
__global__ __launch_bounds__(256) void topk_scan(
    float* __restrict__ att, int* __restrict__ candM,
    int* __restrict__ cnt_g) {
  __shared__ unsigned red[4];
  __shared__ int lcnt, lg;

  const int n = blockIdx.x;
  const int t = threadIdx.x;
  const int wid = t >> 6, lane = t & 63;
  float* row = att + (size_t)n * N_CTX;

  float ar[16], tr[16];
  unsigned ur[16];
#pragma unroll
  for (int i = 0; i < 4; ++i) {
    float4 v4 = *reinterpret_cast<const float4*>(row + t * 16 + i * 4);
    float tmp[4] = {v4.x, v4.y, v4.z, v4.w};
#pragma unroll
    for (int j = 0; j < 4; ++j) {
      float a = tmp[j];
      float tt = (a > EPS_NN) ? a : 0.0f;
      ar[i * 4 + j] = a;
      tr[i * 4 + j] = tt;
      ur[i * 4 + j] = __float_as_uint(tt);
    }
  }

  unsigned lo = 0u, hi = 0x7F800000u;
  while (lo < hi) {
    unsigned mid = lo + ((hi - lo) >> 1);
    unsigned c = 0;
#pragma unroll
    for (int i = 0; i < 16; ++i) c += (ur[i] > mid) ? 1u : 0u;
#pragma unroll
    for (int off = 32; off; off >>= 1) c += __shfl_down(c, off, 64);
    if (lane == 0) red[wid] = c;
    __syncthreads();
    unsigned tot = red[0] + red[1] + red[2] + red[3];
    __syncthreads();
    if (tot < TOPK_K) hi = mid; else lo = mid + 1;
  }
  const float vk = __uint_as_float(lo);

  if (t == 0) { lcnt = 0; lg = 0; }
  __syncthreads();

  unsigned myg = 0;
#pragma unroll
  for (int i = 0; i < 16; ++i) {
    const int m = t * 16 + i;
    const float a = ar[i], tt = tr[i];
    const bool isEps = fabsf(a - EPS_NN) <= DELTA;
    const bool isOrd = (tt > 0.f) && (fabsf(tt - vk) <= DELTA);
    const bool cand = isEps || isOrd;
    const bool defIn = (tt > vk + DELTA) && !cand;
    tr[i] = defIn ? tt : 0.f;
    myg += defIn ? 1u : 0u;
    if (cand) {
      int pos = atomicAdd(&lcnt, 1);
      if (pos < CAP) candM[n * CAP + pos] = m;
    }
  }
#pragma unroll
  for (int off = 32; off; off >>= 1) myg += __shfl_down(myg, off, 64);
  if (lane == 0) atomicAdd(&lg, (int)myg);

#pragma unroll
  for (int i = 0; i < 4; ++i) {
    *reinterpret_cast<float4*>(row + t * 16 + i * 4) =
        make_float4(tr[i * 4], tr[i * 4 + 1], tr[i * 4 + 2], tr[i * 4 + 3]);
  }
  __syncthreads();
  if (t == 0) {
    cnt_g[2 * n] = (lcnt < CAP) ? lcnt : CAP;
    cnt_g[2 * n + 1] = lg;
  }
}

// ---------------------------------------------------------------------------
// Kernel 4: exact repair + select (UNCHANGED from R9).
// ---------------------------------------------------------------------------
__global__ __launch_bounds__(64) void repair_select(
    const float* __restrict__ ctx, const float* __restrict__ w,
    const float* __restrict__ invr, const int* __restrict__ candM,
    const int* __restrict__ cnt_g, float* __restrict__ att) {
  const int n = blockIdx.x;
  const int c = cnt_g[2 * n];
  if (c == 0) return;
  const int slots = TOPK_K - cnt_g[2 * n + 1];

  __shared__ float te_s[CAP];
  __shared__ int m_s[CAP];

  const int j = threadIdx.x;
  float te = -1.f;
  int m = -1;
  if (j < c) {
    m = candM[n * CAP + j];
    const float* cn = ctx + (size_t)n * DIM;
    const float* cm = ctx + (size_t)m * DIM;
    float e = 0.f;
    for (int p = 0; p < NPERS; ++p) {
      const float sA = invr[(size_t)p * N_CTX + n];
      const float sB = invr[(size_t)p * N_CTX + m];
      const float* wp = w + (size_t)p * DIM;
      for (int d = 0; d < DIM; ++d)
        e = fmaf((cn[d] * wp[d]) * sA, (cm[d] * wp[d]) * sB, e);
    }
    te = (e > EPS_NN) ? e : 0.f;
  }
  m_s[j] = m;
  te_s[j] = te;
  __syncthreads();
  if (j < c) {
    int rank = 0;
    for (int i = 0; i < c; ++i) {
      if (i == j) continue;
      rank += ((te_s[i] > te) || (te_s[i] == te && m_s[i] < m)) ? 1 : 0;
    }
    if (rank < slots) att[(size_t)n * N_CTX + m] = te;
  }
}

// ---------------------------------------------------------------------------
extern "C" void kernel_launch(void* const* d_in, const int* in_sizes, int n_in,
                              void* d_out, int out_size, void* d_ws, size_t ws_size,
                              hipStream_t stream) {
  const float* ctx = (const float*)d_in[0];   // (4096, 512)
  const float* w   = (const float*)d_in[1];   // (16, 512)
  float* out = (float*)d_out;                 // (4096, 4096)

  // ws: invr (256 KB) | cnt_g (32 KB) | candM (1 MB) | Fhi (64 MB) | Flo (64 MB)
  const size_t OFF_CNT = 262144;
  const size_t OFF_CAND = OFF_CNT + 32768;
  const size_t OFF_FHI = OFF_CAND + 1048576;   // 1343488
  const size_t FSZ = (size_t)32 * NKSTEP * CHUNK;  // 67108864
  float* invr = (float*)d_ws;
  int* cnt_g = (int*)((char*)d_ws + OFF_CNT);
  int* candM = (int*)((char*)d_ws + OFF_CAND);
  unsigned short* Fhi = (unsigned short*)((char*)d_ws + OFF_FHI);
  unsigned short* Flo = (unsigned short*)((char*)d_ws + OFF_FHI + FSZ);

  norms_kernel<<<(NPERS * N_CTX) / 4, 256, 0, stream>>>(ctx, w, invr);

  if (ws_size >= OFF_FHI + 2 * FSZ) {
    split_kernel<<<(N_CTX * (KTOT / 8)) / 256, 256, 0, stream>>>(ctx, w, invr, Fhi, Flo);
    att_gemm_fast<<<528, 256, 0, stream>>>(Fhi, Flo, out);
  } else {
    dim3 grid(N_CTX / BM, N_CTX / BM);
    att_gemm<<<grid, 256, 0, stream>>>(ctx, w, invr, out);
  }

  topk_scan<<<N_CTX, 256, 0, stream>>>(out, candM, cnt_g);
  repair_select<<<N_CTX, 64, 0, stream>>>(ctx, w, invr, candM, cnt_g, out);
}

// Round 11
// 1001.893 us; speedup vs baseline: 11.4880x; 1.0126x over previous
//
#include <hip/hip_runtime.h>
#include <math.h>
#include <stdint.h>

#define N_CTX 4096
#define DIM 512
#define NPERS 16
#define KTOT (NPERS * DIM)   // 8192
#define EPS_NN 0.1f
#define TOPK_K 30

#define DELTA 1e-3f          // ambiguity margin (>> worst approx-vs-exact error)
#define CAP 64               // max candidates per row

#define BM 128               // MFMA output tile
#define BK 64                // K-step (bf16 elems)
#define NKSTEP (KTOT / BK)   // 128
#define CHUNK 16384          // bytes per (panel, k-step) LDS image

typedef __attribute__((ext_vector_type(8))) short bfrag;   // 8 bf16 = 4 VGPR
typedef __attribute__((ext_vector_type(4))) float f32x4;

// round-to-nearest-even float -> bf16 bits
__device__ __forceinline__ unsigned short f2bf(float f) {
  unsigned u = __float_as_uint(f);
  unsigned r = u + 0x7FFFu + ((u >> 16) & 1u);
  return (unsigned short)(r >> 16);
}

#define SWZ(r, b) ((b) ^ (((r) & 7) << 4))

// stage 1 KB: 64 lanes x 16 B. ldst = wave-uniform LDS base; HW adds lane*16.
__device__ __forceinline__ void stage1k(const char* gsrc, char* ldst, int lane) {
#if __has_builtin(__builtin_amdgcn_global_load_lds)
  __builtin_amdgcn_global_load_lds(
      (const __attribute__((address_space(1))) unsigned int*)(uintptr_t)(gsrc + lane * 16),
      (__attribute__((address_space(3))) unsigned int*)(uintptr_t)ldst, 16, 0, 0);
#else
  *reinterpret_cast<uint4*>(ldst + lane * 16) =
      *reinterpret_cast<const uint4*>(gsrc + lane * 16);
#endif
}

// ---------------------------------------------------------------------------
// Kernel 1: invr[p][n] = 0.25 / max(||context[n] * weight[p]||, 1e-12)
// UNCHANGED (bit-identical invr feeds split, fallback GEMM and exact repair).
// ---------------------------------------------------------------------------
__global__ __launch_bounds__(256) void norms_kernel(
    const float* __restrict__ ctx, const float* __restrict__ w,
    float* __restrict__ invr) {
  int wid = threadIdx.x >> 6;
  int lane = threadIdx.x & 63;
  int gid = blockIdx.x * 4 + wid;          // 0 .. 65535
  int p = gid >> 12;
  int n = gid & (N_CTX - 1);
  const float4* c4 = reinterpret_cast<const float4*>(ctx + (size_t)n * DIM + lane * 8);
  const float4* w4 = reinterpret_cast<const float4*>(w + (size_t)p * DIM + lane * 8);
  float4 c0 = c4[0], c1 = c4[1];
  float4 w0 = w4[0], w1 = w4[1];
  float s = 0.f, v;
  v = c0.x * w0.x; s = fmaf(v, v, s);
  v = c0.y * w0.y; s = fmaf(v, v, s);
  v = c0.z * w0.z; s = fmaf(v, v, s);
  v = c0.w * w0.w; s = fmaf(v, v, s);
  v = c1.x * w1.x; s = fmaf(v, v, s);
  v = c1.y * w1.y; s = fmaf(v, v, s);
  v = c1.z * w1.z; s = fmaf(v, v, s);
  v = c1.w * w1.w; s = fmaf(v, v, s);
#pragma unroll
  for (int off = 32; off; off >>= 1) s += __shfl_down(s, off, 64);
  if (lane == 0) invr[(size_t)p * N_CTX + n] = 0.25f / fmaxf(sqrtf(s), 1e-12f);
}

// ---------------------------------------------------------------------------
// Kernel 1b: split F = hi + lo (bf16 RNE, same math as before) into the
// panel-swizzled LDS-image layout. R11: thread <-> (n, 8-col block), loops
// p internally -> ctx read once (was 16x), invr loads wave-uniform.
// Index algebra identical to R10: s*64+sl*8 == p*512+db*8.
// ---------------------------------------------------------------------------
__global__ __launch_bounds__(256) void split_kernel(
    const float* __restrict__ ctx, const float* __restrict__ w,
    const float* __restrict__ invr, unsigned short* __restrict__ Fhi,
    unsigned short* __restrict__ Flo) {
  const int tid = blockIdx.x * 256 + threadIdx.x;   // 0 .. 4096*64-1
  const int n = tid >> 6;
  const int db = tid & 63;                // 8-col block within the 512-dim
  const int d0 = db * 8;
  const int P = n >> 7;                   // panel
  const int r = n & 127;                  // row within panel
  const int sl = db & 7;                  // 16B slot within k-step chunk
  const int swzoff = r * 128 + ((sl * 16) ^ ((r & 7) << 4));

  const float4 c0 = *reinterpret_cast<const float4*>(ctx + (size_t)n * DIM + d0);
  const float4 c1 = *reinterpret_cast<const float4*>(ctx + (size_t)n * DIM + d0 + 4);

#pragma unroll
  for (int p = 0; p < NPERS; ++p) {
    const float4 w0 = *reinterpret_cast<const float4*>(w + (size_t)p * DIM + d0);
    const float4 w1 = *reinterpret_cast<const float4*>(w + (size_t)p * DIM + d0 + 4);
    const float sc = invr[(size_t)p * N_CTX + n];

    float f[8] = {c0.x * w0.x * sc, c0.y * w0.y * sc, c0.z * w0.z * sc, c0.w * w0.w * sc,
                  c1.x * w1.x * sc, c1.y * w1.y * sc, c1.z * w1.z * sc, c1.w * w1.w * sc};
    unsigned hb[8], lb[8];
#pragma unroll
    for (int j = 0; j < 8; ++j) {
      hb[j] = f2bf(f[j]);
      float hf = __uint_as_float(hb[j] << 16);
      lb[j] = f2bf(f[j] - hf);
    }
    uint4 hv = make_uint4(hb[0] | (hb[1] << 16), hb[2] | (hb[3] << 16),
                          hb[4] | (hb[5] << 16), hb[6] | (hb[7] << 16));
    uint4 lv = make_uint4(lb[0] | (lb[1] << 16), lb[2] | (lb[3] << 16),
                          lb[4] | (lb[5] << 16), lb[6] | (lb[7] << 16));
    const int s = p * 8 + (db >> 3);      // k-step index
    const size_t base = (size_t)(P * 128 + s) * CHUNK + swzoff;
    *reinterpret_cast<uint4*>((char*)Fhi + base) = hv;
    *reinterpret_cast<uint4*>((char*)Flo + base) = lv;
  }
}

// ---------------------------------------------------------------------------
// Kernel 2 (fast): att = F F^T via bf16 MFMA, 3 products (hh, hl, lh).
// UNCHANGED from R10 (496 us, MfmaUtil 38%, validated).
// ---------------------------------------------------------------------------
__global__ __launch_bounds__(256, 2) void att_gemm_fast(
    const unsigned short* __restrict__ Fhi, const unsigned short* __restrict__ Flo,
    float* __restrict__ out) {
  int bid = blockIdx.x;
  int by = 0;
  while (bid >= (by + 1) * 32 - ((by + 1) * by) / 2) ++by;
  const int bx = by + (bid - (by * 32 - (by * (by - 1)) / 2));

  __shared__ __align__(16) char Ahi[CHUNK];
  __shared__ __align__(16) char Alo[CHUNK];
  __shared__ __align__(16) char Bhi[CHUNK];
  __shared__ __align__(16) char Blo[CHUNK];

  const int t = threadIdx.x;
  const int lane = t & 63, wid = t >> 6;
  const int wr = wid >> 1, wc = wid & 1;
  const int woff = __builtin_amdgcn_readfirstlane(wid * 4096);

  const char* gAh = (const char*)Fhi + (size_t)by * NKSTEP * CHUNK + woff;
  const char* gAl = (const char*)Flo + (size_t)by * NKSTEP * CHUNK + woff;
  const char* gBh = (const char*)Fhi + (size_t)bx * NKSTEP * CHUNK + woff;
  const char* gBl = (const char*)Flo + (size_t)bx * NKSTEP * CHUNK + woff;

  f32x4 acc[4][4] = {};

  for (int s = 0; s < NKSTEP; ++s) {
    const size_t so = (size_t)s * CHUNK;
#pragma unroll
    for (int i = 0; i < 4; ++i) {
      stage1k(gAh + so + i * 1024, Ahi + woff + i * 1024, lane);
      stage1k(gAl + so + i * 1024, Alo + woff + i * 1024, lane);
      stage1k(gBh + so + i * 1024, Bhi + woff + i * 1024, lane);
      stage1k(gBl + so + i * 1024, Blo + woff + i * 1024, lane);
    }
    __syncthreads();   // vmcnt drained before barrier: staged data visible

#pragma unroll
    for (int ks = 0; ks < 2; ++ks) {
      const int kb = ks * 64 + (lane >> 4) * 16;
      bfrag ah[4], al[4], bh[4], bl[4];
#pragma unroll
      for (int m = 0; m < 4; ++m) {
        const int r = wr * 64 + m * 16 + (lane & 15);
        const int off = r * 128 + SWZ(r, kb);
        ah[m] = *reinterpret_cast<const bfrag*>(Ahi + off);
        al[m] = *reinterpret_cast<const bfrag*>(Alo + off);
      }
#pragma unroll
      for (int n2 = 0; n2 < 4; ++n2) {
        const int r = wc * 64 + n2 * 16 + (lane & 15);
        const int off = r * 128 + SWZ(r, kb);
        bh[n2] = *reinterpret_cast<const bfrag*>(Bhi + off);
        bl[n2] = *reinterpret_cast<const bfrag*>(Blo + off);
      }
#pragma unroll
      for (int m = 0; m < 4; ++m)
#pragma unroll
        for (int n2 = 0; n2 < 4; ++n2) {
          acc[m][n2] = __builtin_amdgcn_mfma_f32_16x16x32_bf16(ah[m], bh[n2], acc[m][n2], 0, 0, 0);
          acc[m][n2] = __builtin_amdgcn_mfma_f32_16x16x32_bf16(ah[m], bl[n2], acc[m][n2], 0, 0, 0);
          acc[m][n2] = __builtin_amdgcn_mfma_f32_16x16x32_bf16(al[m], bh[n2], acc[m][n2], 0, 0, 0);
        }
    }
    __syncthreads();   // all waves done reading before next overwrite
  }

  const int Ro = by * BM, Co = bx * BM;
  const int col = lane & 15, rq = (lane >> 4) * 4;
#pragma unroll
  for (int m = 0; m < 4; ++m)
#pragma unroll
    for (int n2 = 0; n2 < 4; ++n2) {
      const int gr = Ro + wr * 64 + m * 16 + rq;
      const int gc = Co + wc * 64 + n2 * 16 + col;
#pragma unroll
      for (int j = 0; j < 4; ++j)
        out[(size_t)(gr + j) * N_CTX + gc] = acc[m][n2][j];
      if (bx != by) {
        *reinterpret_cast<float4*>(out + (size_t)gc * N_CTX + gr) =
            make_float4(acc[m][n2][0], acc[m][n2][1], acc[m][n2][2], acc[m][n2][3]);
      }
    }
}

// ---------------------------------------------------------------------------
// Kernel 2 (fallback): on-the-fly split + MFMA (used only if ws too small).
// ---------------------------------------------------------------------------
__device__ __forceinline__ void stage_half(char* __restrict__ hi_base,
                                           char* __restrict__ lo_base,
                                           const float4* cv, const float4* wv,
                                           float s, int r, int h) {
  unsigned hu[16], lu[16];
#pragma unroll
  for (int i = 0; i < 8; ++i) {
    float f[4] = {cv[i].x * wv[i].x * s, cv[i].y * wv[i].y * s,
                  cv[i].z * wv[i].z * s, cv[i].w * wv[i].w * s};
    unsigned hb[4], lb[4];
#pragma unroll
    for (int j = 0; j < 4; ++j) {
      hb[j] = f2bf(f[j]);
      float hf = __uint_as_float(hb[j] << 16);
      lb[j] = f2bf(f[j] - hf);
    }
    hu[2 * i] = hb[0] | (hb[1] << 16);
    hu[2 * i + 1] = hb[2] | (hb[3] << 16);
    lu[2 * i] = lb[0] | (lb[1] << 16);
    lu[2 * i + 1] = lb[2] | (lb[3] << 16);
  }
#pragma unroll
  for (int c = 0; c < 4; ++c) {
    int boff = r * 128 + SWZ(r, h * 64 + c * 16);
    *reinterpret_cast<uint4*>(hi_base + boff) =
        make_uint4(hu[4 * c], hu[4 * c + 1], hu[4 * c + 2], hu[4 * c + 3]);
    *reinterpret_cast<uint4*>(lo_base + boff) =
        make_uint4(lu[4 * c], lu[4 * c + 1], lu[4 * c + 2], lu[4 * c + 3]);
  }
}

__global__ __launch_bounds__(256, 2) void att_gemm(
    const float* __restrict__ ctx, const float* __restrict__ w,
    const float* __restrict__ invr, float* __restrict__ out) {
  const int bx = blockIdx.x, by = blockIdx.y;
  if (by > bx) return;

  __shared__ __align__(16) char Ahi[BM * 128];
  __shared__ __align__(16) char Alo[BM * 128];
  __shared__ __align__(16) char Bhi[BM * 128];
  __shared__ __align__(16) char Blo[BM * 128];

  const int t = threadIdx.x;
  const int lane = t & 63, wid = t >> 6;
  const int wr = wid >> 1, wc = wid & 1;
  const int Ro = by * BM, Co = bx * BM;
  const int srow = t >> 1;
  const int sh = t & 1;

  f32x4 acc[4][4] = {};

  for (int k0 = 0; k0 < KTOT; k0 += BK) {
    const int p = k0 >> 9;
    const int d0 = (k0 & (DIM - 1)) + sh * 32;

    float4 cva[8], cvb[8], wv[8];
    const float* wrow = w + (size_t)p * DIM + d0;
    const float* arow = ctx + (size_t)(Ro + srow) * DIM + d0;
    const float* brow = ctx + (size_t)(Co + srow) * DIM + d0;
#pragma unroll
    for (int i = 0; i < 8; ++i) {
      wv[i] = *reinterpret_cast<const float4*>(wrow + 4 * i);
      cva[i] = *reinterpret_cast<const float4*>(arow + 4 * i);
      cvb[i] = *reinterpret_cast<const float4*>(brow + 4 * i);
    }
    const float sA = invr[(size_t)p * N_CTX + Ro + srow];
    const float sB = invr[(size_t)p * N_CTX + Co + srow];

    __syncthreads();
    stage_half(Ahi, Alo, cva, wv, sA, srow, sh);
    stage_half(Bhi, Blo, cvb, wv, sB, srow, sh);
    __syncthreads();

#pragma unroll
    for (int ks = 0; ks < 2; ++ks) {
      const int kb = ks * 64 + (lane >> 4) * 16;
      bfrag ah[4], al[4], bh[4], bl[4];
#pragma unroll
      for (int m = 0; m < 4; ++m) {
        const int r = wr * 64 + m * 16 + (lane & 15);
        const int off = r * 128 + SWZ(r, kb);
        ah[m] = *reinterpret_cast<const bfrag*>(Ahi + off);
        al[m] = *reinterpret_cast<const bfrag*>(Alo + off);
      }
#pragma unroll
      for (int n = 0; n < 4; ++n) {
        const int r = wc * 64 + n * 16 + (lane & 15);
        const int off = r * 128 + SWZ(r, kb);
        bh[n] = *reinterpret_cast<const bfrag*>(Bhi + off);
        bl[n] = *reinterpret_cast<const bfrag*>(Blo + off);
      }
#pragma unroll
      for (int m = 0; m < 4; ++m)
#pragma unroll
        for (int n = 0; n < 4; ++n) {
          acc[m][n] = __builtin_amdgcn_mfma_f32_16x16x32_bf16(ah[m], bh[n], acc[m][n], 0, 0, 0);
          acc[m][n] = __builtin_amdgcn_mfma_f32_16x16x32_bf16(ah[m], bl[n], acc[m][n], 0, 0, 0);
          acc[m][n] = __builtin_amdgcn_mfma_f32_16x16x32_bf16(al[m], bh[n], acc[m][n], 0, 0, 0);
        }
    }
  }

  const int col = lane & 15, rq = (lane >> 4) * 4;
#pragma unroll
  for (int m = 0; m < 4; ++m)
#pragma unroll
    for (int n = 0; n < 4; ++n) {
      const int gr = Ro + wr * 64 + m * 16 + rq;
      const int gc = Co + wc * 64 + n * 16 + col;
#pragma unroll
      for (int j = 0; j < 4; ++j)
        out[(size_t)(gr + j) * N_CTX + gc] = acc[m][n][j];
      if (bx != by) {
        *reinterpret_cast<float4*>(out + (size_t)gc * N_CTX + gr) =
            make_float4(acc[m][n][0], acc[m][n][1], acc[m][n][2], acc[m][n][3]);
      }
    }
}

// ---------------------------------------------------------------------------
// Kernel 3: scan. R11 change: eps-crossers are candidates ONLY when the row's
// approx 30th value vk is near eps (vk <= eps + 2*DELTA). If vk > eps+2*DELTA,
// an eps-crosser's exact value (<= eps+DELTA+err) is strictly below >=30 exact
// values (>= vk-err) -> provably outside the exact top-30 AND eps-maskable ->
// output 0 either way. Output bits unchanged vs R10.
// ---------------------------------------------------------------------------
__global__ __launch_bounds__(256) void topk_scan(
    float* __restrict__ att, int* __restrict__ candM,
    int* __restrict__ cnt_g) {
  __shared__ unsigned red[4];
  __shared__ int lcnt, lg;

  const int n = blockIdx.x;
  const int t = threadIdx.x;
  const int wid = t >> 6, lane = t & 63;
  float* row = att + (size_t)n * N_CTX;

  float ar[16], tr[16];
  unsigned ur[16];
#pragma unroll
  for (int i = 0; i < 4; ++i) {
    float4 v4 = *reinterpret_cast<const float4*>(row + t * 16 + i * 4);
    float tmp[4] = {v4.x, v4.y, v4.z, v4.w};
#pragma unroll
    for (int j = 0; j < 4; ++j) {
      float a = tmp[j];
      float tt = (a > EPS_NN) ? a : 0.0f;
      ar[i * 4 + j] = a;
      tr[i * 4 + j] = tt;
      ur[i * 4 + j] = __float_as_uint(tt);
    }
  }

  unsigned lo = 0u, hi = 0x7F800000u;
  while (lo < hi) {
    unsigned mid = lo + ((hi - lo) >> 1);
    unsigned c = 0;
#pragma unroll
    for (int i = 0; i < 16; ++i) c += (ur[i] > mid) ? 1u : 0u;
#pragma unroll
    for (int off = 32; off; off >>= 1) c += __shfl_down(c, off, 64);
    if (lane == 0) red[wid] = c;
    __syncthreads();
    unsigned tot = red[0] + red[1] + red[2] + red[3];
    __syncthreads();
    if (tot < TOPK_K) hi = mid; else lo = mid + 1;
  }
  const float vk = __uint_as_float(lo);
  const bool nearEps = (vk <= EPS_NN + 2.0f * DELTA);

  if (t == 0) { lcnt = 0; lg = 0; }
  __syncthreads();

  unsigned myg = 0;
#pragma unroll
  for (int i = 0; i < 16; ++i) {
    const int m = t * 16 + i;
    const float a = ar[i], tt = tr[i];
    const bool isEps = fabsf(a - EPS_NN) <= DELTA;
    const bool isOrd = (tt > 0.f) && (fabsf(tt - vk) <= DELTA);
    const bool cand = isOrd || (isEps && nearEps);
    const bool defIn = (tt > vk + DELTA) && !cand;
    tr[i] = defIn ? tt : 0.f;
    myg += defIn ? 1u : 0u;
    if (cand) {
      int pos = atomicAdd(&lcnt, 1);
      if (pos < CAP) candM[n * CAP + pos] = m;
    }
  }
#pragma unroll
  for (int off = 32; off; off >>= 1) myg += __shfl_down(myg, off, 64);
  if (lane == 0) atomicAdd(&lg, (int)myg);

#pragma unroll
  for (int i = 0; i < 4; ++i) {
    *reinterpret_cast<float4*>(row + t * 16 + i * 4) =
        make_float4(tr[i * 4], tr[i * 4 + 1], tr[i * 4 + 2], tr[i * 4 + 3]);
  }
  __syncthreads();
  if (t == 0) {
    cnt_g[2 * n] = (lcnt < CAP) ? lcnt : CAP;
    cnt_g[2 * n + 1] = lg;
  }
}

// ---------------------------------------------------------------------------
// Kernel 4: exact repair + select. R11: float4-batched operand loads (VMEM
// instrs /4); fmaf chain and operand expressions IDENTICAL to R2/R9/R10
// ((cn*w)*sA against (cm*w)*sB, k ascending) -> bit-identical values.
// ---------------------------------------------------------------------------
__global__ __launch_bounds__(64) void repair_select(
    const float* __restrict__ ctx, const float* __restrict__ w,
    const float* __restrict__ invr, const int* __restrict__ candM,
    const int* __restrict__ cnt_g, float* __restrict__ att) {
  const int n = blockIdx.x;
  const int c = cnt_g[2 * n];
  if (c == 0) return;
  const int slots = TOPK_K - cnt_g[2 * n + 1];

  __shared__ float te_s[CAP];
  __shared__ int m_s[CAP];

  const int j = threadIdx.x;
  float te = -1.f;
  int m = -1;
  if (j < c) {
    m = candM[n * CAP + j];
    const float4* cn4 = reinterpret_cast<const float4*>(ctx + (size_t)n * DIM);
    const float4* cm4 = reinterpret_cast<const float4*>(ctx + (size_t)m * DIM);
    float e = 0.f;
    for (int p = 0; p < NPERS; ++p) {
      const float sA = invr[(size_t)p * N_CTX + n];
      const float sB = invr[(size_t)p * N_CTX + m];
      const float4* w4 = reinterpret_cast<const float4*>(w + (size_t)p * DIM);
#pragma unroll 4
      for (int q = 0; q < DIM / 4; ++q) {
        const float4 a = cn4[q], b = cm4[q], ww = w4[q];
        e = fmaf((a.x * ww.x) * sA, (b.x * ww.x) * sB, e);
        e = fmaf((a.y * ww.y) * sA, (b.y * ww.y) * sB, e);
        e = fmaf((a.z * ww.z) * sA, (b.z * ww.z) * sB, e);
        e = fmaf((a.w * ww.w) * sA, (b.w * ww.w) * sB, e);
      }
    }
    te = (e > EPS_NN) ? e : 0.f;
  }
  m_s[j] = m;
  te_s[j] = te;
  __syncthreads();
  if (j < c) {
    int rank = 0;
    for (int i = 0; i < c; ++i) {
      if (i == j) continue;
      rank += ((te_s[i] > te) || (te_s[i] == te && m_s[i] < m)) ? 1 : 0;
    }
    if (rank < slots) att[(size_t)n * N_CTX + m] = te;
  }
}

// ---------------------------------------------------------------------------
extern "C" void kernel_launch(void* const* d_in, const int* in_sizes, int n_in,
                              void* d_out, int out_size, void* d_ws, size_t ws_size,
                              hipStream_t stream) {
  const float* ctx = (const float*)d_in[0];   // (4096, 512)
  const float* w   = (const float*)d_in[1];   // (16, 512)
  float* out = (float*)d_out;                 // (4096, 4096)

  // ws: invr (256 KB) | cnt_g (32 KB) | candM (1 MB) | Fhi (64 MB) | Flo (64 MB)
  const size_t OFF_CNT = 262144;
  const size_t OFF_CAND = OFF_CNT + 32768;
  const size_t OFF_FHI = OFF_CAND + 1048576;
  const size_t FSZ = (size_t)32 * NKSTEP * CHUNK;  // 67108864
  float* invr = (float*)d_ws;
  int* cnt_g = (int*)((char*)d_ws + OFF_CNT);
  int* candM = (int*)((char*)d_ws + OFF_CAND);
  unsigned short* Fhi = (unsigned short*)((char*)d_ws + OFF_FHI);
  unsigned short* Flo = (unsigned short*)((char*)d_ws + OFF_FHI + FSZ);

  norms_kernel<<<(NPERS * N_CTX) / 4, 256, 0, stream>>>(ctx, w, invr);

  if (ws_size >= OFF_FHI + 2 * FSZ) {
    split_kernel<<<(N_CTX * 64) / 256, 256, 0, stream>>>(ctx, w, invr, Fhi, Flo);
    att_gemm_fast<<<528, 256, 0, stream>>>(Fhi, Flo, out);
  } else {
    dim3 grid(N_CTX / BM, N_CTX / BM);
    att_gemm<<<grid, 256, 0, stream>>>(ctx, w, invr, out);
  }

  topk_scan<<<N_CTX, 256, 0, stream>>>(out, candM, cnt_g);
  repair_select<<<N_CTX, 64, 0, stream>>>(ctx, w, invr, candM, cnt_g, out);
}